// Round 4
// baseline (956.059 us; speedup 1.0000x reference)
//
#include <hip/hip_runtime.h>

typedef unsigned short u16;
typedef unsigned int u32;
typedef unsigned char u8;

typedef __attribute__((ext_vector_type(8))) short bf16x8;
typedef __attribute__((ext_vector_type(4))) float f32x4;

__device__ __forceinline__ float bf2f(u16 u) {
    union { u32 i; float f; } v; v.i = ((u32)u) << 16; return v.f;
}
__device__ __forceinline__ u16 f2bf(float f) {
    union { float f; u32 i; } v; v.f = f;
    u32 r = v.i + 0x7fffu + ((v.i >> 16) & 1u);
    return (u16)(r >> 16);
}

// async global->LDS, 16B per lane; lds must be wave-uniform (lane*16 added by HW)
__device__ __forceinline__ void async16(u16* lds, const u16* g) {
    __builtin_amdgcn_global_load_lds(
        (const __attribute__((address_space(1))) void*)g,
        (__attribute__((address_space(3))) void*)lds, 16, 0, 0);
}

// ------------------------------------------------------------- dtype detect
__global__ __launch_bounds__(256) void detect_dtype(const u32* __restrict__ x,
                                                    int* __restrict__ flag) {
    int tid = threadIdx.x;
    int hits = 0;
    for (int i = 0; i < 4; ++i) {
        u32 w = x[tid * 4 + i];
        u32 e = (w >> 7) & 0xFFu;
        hits += (e >= 110u && e <= 131u) ? 1 : 0;
    }
    for (int off = 1; off < 64; off <<= 1) hits += __shfl_xor(hits, off, 64);
    __shared__ int red[4];
    int wave = tid >> 6, lane = tid & 63;
    if (lane == 0) red[wave] = hits;
    __syncthreads();
    if (tid == 0) flag[0] = (red[0] + red[1] + red[2] + red[3] > 512) ? 1 : 0;
}

// ------------------------------------------------------------- convert pass
// src (bf16 copy or fp32 convert per flag) -> dst bf16. 8 elems/thread.
__global__ __launch_bounds__(256) void conv_bf16(const void* __restrict__ src,
                                                 u16* __restrict__ dst,
                                                 const int* __restrict__ flagp) {
    int flag = *flagp;
    size_t i = (size_t)blockIdx.x * 256 + threadIdx.x;
    if (flag) {
        ((uint4*)dst)[i] = ((const uint4*)src)[i];
    } else {
        const float4* s = (const float4*)src + i * 2;
        float4 f0 = s[0], f1 = s[1];
        u16 t[8];
        t[0] = f2bf(f0.x); t[1] = f2bf(f0.y); t[2] = f2bf(f0.z); t[3] = f2bf(f0.w);
        t[4] = f2bf(f1.x); t[5] = f2bf(f1.y); t[6] = f2bf(f1.z); t[7] = f2bf(f1.w);
        ((uint4*)dst)[i] = *(const uint4*)t;
    }
}

// ------------------------------------------------------------- mask pack
__global__ __launch_bounds__(256) void mask_pack(const int* __restrict__ m,
                                                 u8* __restrict__ o) {
    size_t i = (size_t)blockIdx.x * 256 + threadIdx.x;
    const int4* mp = (const int4*)m + i * 4;
    uint4 out;
    u32* op = (u32*)&out;
    for (int j = 0; j < 4; ++j) {
        int4 a = mp[j];
        op[j] = (a.x == 0 ? 0xFFu : 0u) | (a.y == 0 ? 0xFF00u : 0u) |
                (a.z == 0 ? 0xFF0000u : 0u) | (a.w == 0 ? 0xFF000000u : 0u);
    }
    ((uint4*)o)[i] = out;
}

// ---------------------------------------------------------------- LayerNorm
__global__ __launch_bounds__(256) void ln_kernel(const void* __restrict__ x_,
                                                 const void* __restrict__ g_,
                                                 const void* __restrict__ b_,
                                                 u16* __restrict__ out,
                                                 const int* __restrict__ flagp) {
    int flag = *flagp;
    int row = blockIdx.x;
    int tid = threadIdx.x;
    float v[4];
    if (flag) {
        const u16* xr = (const u16*)x_ + (size_t)row * 1024;
        uint2 d = *(const uint2*)&xr[tid * 4];
        v[0] = bf2f((u16)(d.x & 0xffff));
        v[1] = bf2f((u16)(d.x >> 16));
        v[2] = bf2f((u16)(d.y & 0xffff));
        v[3] = bf2f((u16)(d.y >> 16));
    } else {
        const float* xr = (const float*)x_ + (size_t)row * 1024;
        float4 d = *(const float4*)&xr[tid * 4];
        v[0] = d.x; v[1] = d.y; v[2] = d.z; v[3] = d.w;
    }
    float s  = v[0] + v[1] + v[2] + v[3];
    float ss = v[0]*v[0] + v[1]*v[1] + v[2]*v[2] + v[3]*v[3];
    for (int off = 1; off < 64; off <<= 1) {
        s  += __shfl_xor(s,  off, 64);
        ss += __shfl_xor(ss, off, 64);
    }
    __shared__ float red[8];
    int wave = tid >> 6, lane = tid & 63;
    if (lane == 0) { red[wave] = s; red[4 + wave] = ss; }
    __syncthreads();
    s  = red[0] + red[1] + red[2] + red[3];
    ss = red[4] + red[5] + red[6] + red[7];
    float mu   = s * (1.0f / 1024.0f);
    float var  = ss * (1.0f / 1024.0f) - mu * mu;
    float rstd = rsqrtf(var + 1e-5f);
    u16 r01[4];
    for (int j = 0; j < 4; ++j) {
        float g, bb;
        if (flag) { g = bf2f(((const u16*)g_)[tid * 4 + j]); bb = bf2f(((const u16*)b_)[tid * 4 + j]); }
        else      { g = ((const float*)g_)[tid * 4 + j];     bb = ((const float*)b_)[tid * 4 + j]; }
        r01[j] = f2bf((v[j] - mu) * rstd * g + bb);
    }
    uint2 o;
    o.x = (u32)r01[0] | ((u32)r01[1] << 16);
    o.y = (u32)r01[2] | ((u32)r01[3] << 16);
    *(uint2*)&out[(size_t)row * 1024 + tid * 4] = o;
}

// ---------------------------------------------------------------- Transpose
__global__ __launch_bounds__(256) void transpose64(const void* __restrict__ src_,
                                                   u16* __restrict__ dst,
                                                   int rows, int cols,
                                                   const int* __restrict__ flagp) {
    __shared__ u16 t[64][65];
    int flag = *flagp;
    int bx = blockIdx.x * 64;
    int by = blockIdx.y * 64;
    int tid = threadIdx.x;
    for (int i = 0; i < 16; ++i) {
        int r = i * 4 + (tid >> 6);
        int c = tid & 63;
        size_t idx = (size_t)(by + r) * cols + bx + c;
        t[r][c] = flag ? ((const u16*)src_)[idx] : f2bf(((const float*)src_)[idx]);
    }
    __syncthreads();
    for (int i = 0; i < 16; ++i) {
        int r = i * 4 + (tid >> 6);
        int c = tid & 63;
        dst[(size_t)(bx + r) * rows + by + c] = t[c][r];
    }
}

// ------------------------------------------------------- GEMM 128x128 (B^T)
// C[M,N] = cscale * A[M,K] * Bt[N,K]^T, A/Bt bf16.
// BK=64, global_load_lds staging, XOR-swizzled LDS (chunk c of row r at pos
// c^(r&7); no padding allowed by global_load_lds). 4 waves in 2x2, each
// 64x64 = 4x4 of 16x16x32 MFMA.
// vt_mode: write C as vT[b(4)][h(16)][d(64)][kv(2048)] (M=8192=b*kv, N=h*d).
// c_flagged && flag==0: fp32 C store.
__global__ __launch_bounds__(256) void gemm128(const u16* __restrict__ A,
                                               const u16* __restrict__ Bt,
                                               void* __restrict__ C_,
                                               int M, int N, int K,
                                               const int* __restrict__ flagp,
                                               int c_flagged, float cscale,
                                               int vt_mode) {
    __shared__ u16 As[128 * 64];
    __shared__ u16 Bs[128 * 64];
    int flag = *flagp;
    bool c_bf16 = c_flagged ? (flag != 0) : true;

    int tid  = threadIdx.x;
    int wave = tid >> 6, lane = tid & 63;
    int quad = lane >> 4, l16 = lane & 15;
    size_t bm = (size_t)blockIdx.y * 128;
    size_t bn = (size_t)blockIdx.x * 128;
    int wm = (wave >> 1) * 64, wn = (wave & 1) * 64;

    // staging: wave w covers rows [w*32, w*32+32), 4 insts x 8 rows x 128B.
    // block rows are 8-aligned -> source chunk = (lane&7) ^ (lane>>3).
    int lr  = lane >> 3;                 // row within 8-row block
    int csw = (lane & 7) ^ lr;           // swizzled source 16B-chunk
    const u16* Ag = A  + (bm + wave * 32 + lr) * (size_t)K + csw * 8;
    const u16* Bg = Bt + (bn + wave * 32 + lr) * (size_t)K + csw * 8;
    u16* Al = &As[(wave * 32) * 64];
    u16* Bl = &Bs[(wave * 32) * 64];

    f32x4 acc[4][4];
    for (int i = 0; i < 4; ++i)
        for (int j = 0; j < 4; ++j)
            acc[i][j] = (f32x4){0.f, 0.f, 0.f, 0.f};

    int rsw = l16 & 7;                   // row part of read swizzle

    for (int k0 = 0; k0 < K; k0 += 64) {
        __syncthreads();                 // prior-iter LDS reads done
        for (int i = 0; i < 4; ++i) {
            async16(Al + i * 8 * 64, Ag + (size_t)i * 8 * K + k0);
            async16(Bl + i * 8 * 64, Bg + (size_t)i * 8 * K + k0);
        }
        __syncthreads();                 // drains vmcnt (global_load_lds) + barrier

        for (int ks = 0; ks < 2; ++ks) {
            int chunk = ((ks << 2) | quad) ^ rsw;
            bf16x8 af[4], bfr[4];
            for (int mi = 0; mi < 4; ++mi)
                af[mi]  = *(const bf16x8*)&As[(wm + mi * 16 + l16) * 64 + chunk * 8];
            for (int ni = 0; ni < 4; ++ni)
                bfr[ni] = *(const bf16x8*)&Bs[(wn + ni * 16 + l16) * 64 + chunk * 8];
            for (int mi = 0; mi < 4; ++mi)
                for (int ni = 0; ni < 4; ++ni)
                    acc[mi][ni] = __builtin_amdgcn_mfma_f32_16x16x32_bf16(
                        af[mi], bfr[ni], acc[mi][ni], 0, 0, 0);
        }
    }

    // C/D layout: col = l16, row = quad*4 + r
    if (vt_mode) {
        u16* C = (u16*)C_;
        for (int mi = 0; mi < 4; ++mi)
            for (int ni = 0; ni < 4; ++ni) {
                size_t m = bm + wm + mi * 16 + quad * 4;   // + r = kv rows
                size_t n = bn + wn + ni * 16 + l16;
                size_t bb = m >> 11, kv = m & 2047;
                size_t hh = n >> 6,  d  = n & 63;
                u16 t4[4];
                for (int r = 0; r < 4; ++r) t4[r] = f2bf(acc[mi][ni][r]);
                *(uint2*)&C[((bb * 16 + hh) * 64 + d) * 2048 + kv] = *(const uint2*)t4;
            }
    } else {
        for (int mi = 0; mi < 4; ++mi)
            for (int ni = 0; ni < 4; ++ni)
                for (int r = 0; r < 4; ++r) {
                    size_t row = bm + wm + mi * 16 + quad * 4 + r;
                    size_t col = bn + wn + ni * 16 + l16;
                    float val = acc[mi][ni][r] * cscale;
                    if (c_bf16) ((u16*)C_)[row * N + col]   = f2bf(val);
                    else        ((float*)C_)[row * N + col] = val;
                }
    }
}

// ---------------------------------------------------------------- Attention
// Max-free flash attention (unchanged from round 3).
__global__ __launch_bounds__(256) void attn_kernel(const u16* __restrict__ qg,
                                                   const u16* __restrict__ kg,
                                                   const u16* __restrict__ vtg,
                                                   const u8* __restrict__ masku,
                                                   u16* __restrict__ og) {
    __shared__ u16 Qs[64][72];
    __shared__ u16 Ks[64][72];
    __shared__ u16 Vst[64][72];
    __shared__ u16 Ps[4][16][72];

    const int NQc = 1024, NKVc = 2048, HD = 1024;
    int bid = blockIdx.x;
    int qt = bid & 15;
    int h  = (bid >> 4) & 15;
    int b  = bid >> 8;

    int tid  = threadIdx.x;
    int wave = tid >> 6, lane = tid & 63;
    int quad = lane >> 4, l16 = lane & 15;
    int q0 = qt * 64;

    for (int i = 0; i < 2; ++i) {
        int idx = tid + i * 256;
        int row = idx >> 3;
        int col = (idx & 7) * 8;
        *(uint4*)&Qs[row][col] =
            *(const uint4*)&qg[((size_t)b * NQc + q0 + row) * HD + h * 64 + col];
    }
    __syncthreads();
    bf16x8 aq0 = *(const bf16x8*)&Qs[wave * 16 + l16][quad * 8];
    bf16x8 aq1 = *(const bf16x8*)&Qs[wave * 16 + l16][32 + quad * 8];

    f32x4 O[4], lacc;
    for (int nt = 0; nt < 4; ++nt) O[nt] = (f32x4){0.f, 0.f, 0.f, 0.f};
    lacc = (f32x4){0.f, 0.f, 0.f, 0.f};

    bf16x8 bones;
    for (int j = 0; j < 8; ++j) bones[j] = (short)0x3F80;

    const u8* mrow = masku + ((size_t)b * NQc + q0 + wave * 16 + l16) * NKVc;

    for (int kv0 = 0; kv0 < NKVc; kv0 += 64) {
        __syncthreads();
        for (int i = 0; i < 2; ++i) {
            int idx = tid + i * 256;
            int row = idx >> 3;
            int col = (idx & 7) * 8;
            *(uint4*)&Ks[row][col] =
                *(const uint4*)&kg[((size_t)b * NKVc + kv0 + row) * HD + h * 64 + col];
            *(uint4*)&Vst[row][col] =
                *(const uint4*)&vtg[(((size_t)b * 16 + h) * 64 + row) * NKVc + kv0 + col];
        }
        __syncthreads();

        f32x4 S[4];
        for (int nt = 0; nt < 4; ++nt) {
            bf16x8 bk0 = *(const bf16x8*)&Ks[nt * 16 + l16][quad * 8];
            bf16x8 bk1 = *(const bf16x8*)&Ks[nt * 16 + l16][32 + quad * 8];
            f32x4 s = (f32x4){0.f, 0.f, 0.f, 0.f};
            s = __builtin_amdgcn_mfma_f32_16x16x32_bf16(aq0, bk0, s, 0, 0, 0);
            s = __builtin_amdgcn_mfma_f32_16x16x32_bf16(aq1, bk1, s, 0, 0, 0);
            S[nt] = s;
        }

        for (int nt = 0; nt < 4; ++nt)
            for (int r = 0; r < 4; ++r)
                Ps[wave][quad * 4 + r][nt * 16 + l16] = f2bf(exp2f(S[nt][r]));

        uint2 mv0 = *(const uint2*)&mrow[kv0 + quad * 8];
        uint2 mv1 = *(const uint2*)&mrow[kv0 + 32 + quad * 8];
        uint4 m0, m1;
        m0.x = __builtin_amdgcn_perm(0u, mv0.x, 0x01010000u);
        m0.y = __builtin_amdgcn_perm(0u, mv0.x, 0x03030202u);
        m0.z = __builtin_amdgcn_perm(0u, mv0.y, 0x01010000u);
        m0.w = __builtin_amdgcn_perm(0u, mv0.y, 0x03030202u);
        m1.x = __builtin_amdgcn_perm(0u, mv1.x, 0x01010000u);
        m1.y = __builtin_amdgcn_perm(0u, mv1.x, 0x03030202u);
        m1.z = __builtin_amdgcn_perm(0u, mv1.y, 0x01010000u);
        m1.w = __builtin_amdgcn_perm(0u, mv1.y, 0x03030202u);

        uint4 p0 = *(const uint4*)&Ps[wave][l16][quad * 8];
        uint4 p1 = *(const uint4*)&Ps[wave][l16][32 + quad * 8];
        p0.x &= m0.x; p0.y &= m0.y; p0.z &= m0.z; p0.w &= m0.w;
        p1.x &= m1.x; p1.y &= m1.y; p1.z &= m1.z; p1.w &= m1.w;
        bf16x8 ap0 = *(const bf16x8*)&p0;
        bf16x8 ap1 = *(const bf16x8*)&p1;

        lacc = __builtin_amdgcn_mfma_f32_16x16x32_bf16(ap0, bones, lacc, 0, 0, 0);
        lacc = __builtin_amdgcn_mfma_f32_16x16x32_bf16(ap1, bones, lacc, 0, 0, 0);

        for (int nt = 0; nt < 4; ++nt) {
            bf16x8 bv0 = *(const bf16x8*)&Vst[nt * 16 + l16][quad * 8];
            bf16x8 bv1 = *(const bf16x8*)&Vst[nt * 16 + l16][32 + quad * 8];
            O[nt] = __builtin_amdgcn_mfma_f32_16x16x32_bf16(ap0, bv0, O[nt], 0, 0, 0);
            O[nt] = __builtin_amdgcn_mfma_f32_16x16x32_bf16(ap1, bv1, O[nt], 0, 0, 0);
        }
    }

    float inv[4];
    for (int r = 0; r < 4; ++r) inv[r] = 1.0f / lacc[r];
    for (int nt = 0; nt < 4; ++nt)
        for (int r = 0; r < 4; ++r) {
            int qrow = q0 + wave * 16 + quad * 4 + r;
            int col  = h * 64 + nt * 16 + l16;
            og[((size_t)b * NQc + qrow) * HD + col] = f2bf(O[nt][r] * inv[r]);
        }
}

// ---------------------------------------------------------------- launch
extern "C" void kernel_launch(void* const* d_in, const int* in_sizes, int n_in,
                              void* d_out, int out_size, void* d_ws, size_t ws_size,
                              hipStream_t stream) {
    const void* x     = d_in[0];
    const void* key   = d_in[1];
    const void* value = d_in[2];
    const int*  mask  = (const int*)d_in[3];
    const void* Wq    = d_in[4];
    const void* Wk    = d_in[5];
    const void* Wv    = d_in[6];
    const void* Wo    = d_in[7];
    const void* gamma = d_in[8];
    const void* beta  = d_in[9];

    // ws layout (65 MB total), with time-multiplexed scratch:
    //  @1  xn [8MB]  -> overlaid by mask_u8 after Q-GEMM
    //  @9  q  [8MB] + @17 ao [8MB]  -> together = kb [16MB] before Q-GEMM/attn
    //  @25 k  [16MB]                -> vb [16MB] before K-GEMM
    //  @41 vT [16MB]
    //  @57 Wqt/Wkt/Wvt/Wot [2MB each]
    char* ws = (char*)d_ws;
    int* flag = (int*)(ws);
    u16* xn  = (u16*)(ws + ( 1ull << 20));
    u8*  mu8 = (u8*) (ws + ( 1ull << 20));
    u16* q   = (u16*)(ws + ( 9ull << 20));
    u16* kb  = (u16*)(ws + ( 9ull << 20));   // scratch: bf16 key [8192,1024]
    u16* ao  = (u16*)(ws + (17ull << 20));
    u16* k   = (u16*)(ws + (25ull << 20));
    u16* vb  = (u16*)(ws + (25ull << 20));   // scratch: bf16 value [8192,1024]
    u16* vT  = (u16*)(ws + (41ull << 20));
    u16* Wqt = (u16*)(ws + (57ull << 20));
    u16* Wkt = (u16*)(ws + (59ull << 20));
    u16* Wvt = (u16*)(ws + (61ull << 20));
    u16* Wot = (u16*)(ws + (63ull << 20));

    const float QSCALE = 0.125f * 1.44269504f;   // d^-0.5 * log2(e) for exp2 softmax

    detect_dtype<<<1, 256, 0, stream>>>((const u32*)x, flag);

    ln_kernel<<<4096, 256, 0, stream>>>(x, gamma, beta, xn, flag);

    dim3 tg(16, 16);
    transpose64<<<tg, 256, 0, stream>>>(Wq, Wqt, 1024, 1024, flag);
    transpose64<<<tg, 256, 0, stream>>>(Wk, Wkt, 1024, 1024, flag);
    transpose64<<<tg, 256, 0, stream>>>(Wv, Wvt, 1024, 1024, flag);
    transpose64<<<tg, 256, 0, stream>>>(Wo, Wot, 1024, 1024, flag);

    // key/value -> bf16 scratch (8192*1024 elems = 4096 blocks x 2048 elems)
    conv_bf16<<<4096, 256, 0, stream>>>(key,   kb, flag);
    conv_bf16<<<4096, 256, 0, stream>>>(value, vb, flag);

    // V-GEMM first (reads vb@25, writes vT@41), then K-GEMM (reads kb@9..25,
    // writes k@25 over dead vb), then Q-GEMM (writes q@9 over dead kb).
    gemm128<<<dim3(8, 64), 256, 0, stream>>>(vb, Wvt, vT, 8192, 1024, 1024, flag, 0, 1.0f, 1);
    gemm128<<<dim3(8, 64), 256, 0, stream>>>(kb, Wkt, k,  8192, 1024, 1024, flag, 0, 1.0f, 0);
    gemm128<<<dim3(8, 32), 256, 0, stream>>>(xn, Wqt, q,  4096, 1024, 1024, flag, 0, QSCALE, 0);

    // xn consumed -> overlay with packed mask
    mask_pack<<<2048, 256, 0, stream>>>(mask, mu8);

    attn_kernel<<<1024, 256, 0, stream>>>(q, k, vT, mu8, ao);

    gemm128<<<dim3(8, 32), 256, 0, stream>>>(ao, Wot, d_out, 4096, 1024, 1024, flag, 1, 1.0f, 0);
}

// Round 5
// 410.748 us; speedup vs baseline: 2.3276x; 2.3276x over previous
//
#include <hip/hip_runtime.h>

typedef unsigned short u16;
typedef unsigned int u32;
typedef unsigned char u8;

typedef __attribute__((ext_vector_type(8))) short bf16x8;
typedef __attribute__((ext_vector_type(4))) float f32x4;

__device__ __forceinline__ float bf2f(u16 u) {
    union { u32 i; float f; } v; v.i = ((u32)u) << 16; return v.f;
}
__device__ __forceinline__ u16 f2bf(float f) {
    union { float f; u32 i; } v; v.f = f;
    u32 r = v.i + 0x7fffu + ((v.i >> 16) & 1u);
    return (u16)(r >> 16);
}

// async global->LDS, 16B per lane; lds must be wave-uniform (lane*16 added by HW)
__device__ __forceinline__ void async16(u16* lds, const u16* g) {
    __builtin_amdgcn_global_load_lds(
        (const __attribute__((address_space(1))) void*)g,
        (__attribute__((address_space(3))) void*)lds, 16, 0, 0);
}

// ------------------------------------------------------------- dtype detect
__global__ __launch_bounds__(256) void detect_dtype(const u32* __restrict__ x,
                                                    int* __restrict__ flag) {
    int tid = threadIdx.x;
    int hits = 0;
    for (int i = 0; i < 4; ++i) {
        u32 w = x[tid * 4 + i];
        u32 e = (w >> 7) & 0xFFu;
        hits += (e >= 110u && e <= 131u) ? 1 : 0;
    }
    for (int off = 1; off < 64; off <<= 1) hits += __shfl_xor(hits, off, 64);
    __shared__ int red[4];
    int wave = tid >> 6, lane = tid & 63;
    if (lane == 0) red[wave] = hits;
    __syncthreads();
    if (tid == 0) flag[0] = (red[0] + red[1] + red[2] + red[3] > 512) ? 1 : 0;
}

// ------------------------------------------------------------- convert pass
__global__ __launch_bounds__(256) void conv_bf16(const void* __restrict__ src,
                                                 u16* __restrict__ dst,
                                                 const int* __restrict__ flagp) {
    int flag = *flagp;
    size_t i = (size_t)blockIdx.x * 256 + threadIdx.x;
    if (flag) {
        ((uint4*)dst)[i] = ((const uint4*)src)[i];
    } else {
        const float4* s = (const float4*)src + i * 2;
        float4 f0 = s[0], f1 = s[1];
        u16 t[8];
        t[0] = f2bf(f0.x); t[1] = f2bf(f0.y); t[2] = f2bf(f0.z); t[3] = f2bf(f0.w);
        t[4] = f2bf(f1.x); t[5] = f2bf(f1.y); t[6] = f2bf(f1.z); t[7] = f2bf(f1.w);
        ((uint4*)dst)[i] = *(const uint4*)t;
    }
}

// ------------------------------------------------------------- mask pack
__global__ __launch_bounds__(256) void mask_pack(const int* __restrict__ m,
                                                 u8* __restrict__ o) {
    size_t i = (size_t)blockIdx.x * 256 + threadIdx.x;
    const int4* mp = (const int4*)m + i * 4;
    uint4 out;
    u32* op = (u32*)&out;
    for (int j = 0; j < 4; ++j) {
        int4 a = mp[j];
        op[j] = (a.x == 0 ? 0xFFu : 0u) | (a.y == 0 ? 0xFF00u : 0u) |
                (a.z == 0 ? 0xFF0000u : 0u) | (a.w == 0 ? 0xFF000000u : 0u);
    }
    ((uint4*)o)[i] = out;
}

// ---------------------------------------------------------------- LayerNorm
__global__ __launch_bounds__(256) void ln_kernel(const void* __restrict__ x_,
                                                 const void* __restrict__ g_,
                                                 const void* __restrict__ b_,
                                                 u16* __restrict__ out,
                                                 const int* __restrict__ flagp) {
    int flag = *flagp;
    int row = blockIdx.x;
    int tid = threadIdx.x;
    float v[4];
    if (flag) {
        const u16* xr = (const u16*)x_ + (size_t)row * 1024;
        uint2 d = *(const uint2*)&xr[tid * 4];
        v[0] = bf2f((u16)(d.x & 0xffff));
        v[1] = bf2f((u16)(d.x >> 16));
        v[2] = bf2f((u16)(d.y & 0xffff));
        v[3] = bf2f((u16)(d.y >> 16));
    } else {
        const float* xr = (const float*)x_ + (size_t)row * 1024;
        float4 d = *(const float4*)&xr[tid * 4];
        v[0] = d.x; v[1] = d.y; v[2] = d.z; v[3] = d.w;
    }
    float s  = v[0] + v[1] + v[2] + v[3];
    float ss = v[0]*v[0] + v[1]*v[1] + v[2]*v[2] + v[3]*v[3];
    for (int off = 1; off < 64; off <<= 1) {
        s  += __shfl_xor(s,  off, 64);
        ss += __shfl_xor(ss, off, 64);
    }
    __shared__ float red[8];
    int wave = tid >> 6, lane = tid & 63;
    if (lane == 0) { red[wave] = s; red[4 + wave] = ss; }
    __syncthreads();
    s  = red[0] + red[1] + red[2] + red[3];
    ss = red[4] + red[5] + red[6] + red[7];
    float mu   = s * (1.0f / 1024.0f);
    float var  = ss * (1.0f / 1024.0f) - mu * mu;
    float rstd = rsqrtf(var + 1e-5f);
    u16 r01[4];
    for (int j = 0; j < 4; ++j) {
        float g, bb;
        if (flag) { g = bf2f(((const u16*)g_)[tid * 4 + j]); bb = bf2f(((const u16*)b_)[tid * 4 + j]); }
        else      { g = ((const float*)g_)[tid * 4 + j];     bb = ((const float*)b_)[tid * 4 + j]; }
        r01[j] = f2bf((v[j] - mu) * rstd * g + bb);
    }
    uint2 o;
    o.x = (u32)r01[0] | ((u32)r01[1] << 16);
    o.y = (u32)r01[2] | ((u32)r01[3] << 16);
    *(uint2*)&out[(size_t)row * 1024 + tid * 4] = o;
}

// ---------------------------------------------------------------- Transpose
__global__ __launch_bounds__(256) void transpose64(const void* __restrict__ src_,
                                                   u16* __restrict__ dst,
                                                   int rows, int cols,
                                                   const int* __restrict__ flagp) {
    __shared__ u16 t[64][65];
    int flag = *flagp;
    int bx = blockIdx.x * 64;
    int by = blockIdx.y * 64;
    int tid = threadIdx.x;
    for (int i = 0; i < 16; ++i) {
        int r = i * 4 + (tid >> 6);
        int c = tid & 63;
        size_t idx = (size_t)(by + r) * cols + bx + c;
        t[r][c] = flag ? ((const u16*)src_)[idx] : f2bf(((const float*)src_)[idx]);
    }
    __syncthreads();
    for (int i = 0; i < 16; ++i) {
        int r = i * 4 + (tid >> 6);
        int c = tid & 63;
        dst[(size_t)(bx + r) * rows + by + c] = t[c][r];
    }
}

// ------------------------------------------------------- GEMM 128x128 (B^T)
// C[M,N] = cscale * A[M,K] * Bt[N,K]^T, A/Bt bf16. BK=64, global_load_lds
// staging, XOR-swizzled LDS. All constant loops force-unrolled so acc/frag
// arrays SROA into VGPRs/AGPRs (round-4 failure: un-promoted arrays lived in
// scratch -> 1 GB/dispatch spill traffic, VGPR_Count=72).
// __launch_bounds__(256,2): explicit 256-VGPR budget, 2 waves/EU floor.
__global__ __launch_bounds__(256, 2) void gemm128(const u16* __restrict__ A,
                                                  const u16* __restrict__ Bt,
                                                  void* __restrict__ C_,
                                                  int M, int N, int K,
                                                  const int* __restrict__ flagp,
                                                  int c_flagged, float cscale,
                                                  int vt_mode) {
    __shared__ u16 As[128 * 64];
    __shared__ u16 Bs[128 * 64];
    int flag = *flagp;
    bool c_bf16 = c_flagged ? (flag != 0) : true;

    int tid  = threadIdx.x;
    int wave = tid >> 6, lane = tid & 63;
    int quad = lane >> 4, l16 = lane & 15;
    size_t bm = (size_t)blockIdx.y * 128;
    size_t bn = (size_t)blockIdx.x * 128;
    int wm = (wave >> 1) * 64, wn = (wave & 1) * 64;

    // staging: wave w covers rows [w*32, w*32+32), 4 insts x 8 rows x 128B.
    // block rows 8-aligned -> source chunk = (lane&7) ^ (lane>>3).
    int lr  = lane >> 3;
    int csw = (lane & 7) ^ lr;
    const u16* Ag = A  + (bm + wave * 32 + lr) * (size_t)K + csw * 8;
    const u16* Bg = Bt + (bn + wave * 32 + lr) * (size_t)K + csw * 8;
    u16* Al = &As[(wave * 32) * 64];
    u16* Bl = &Bs[(wave * 32) * 64];

    f32x4 acc[4][4];
#pragma unroll
    for (int i = 0; i < 4; ++i)
#pragma unroll
        for (int j = 0; j < 4; ++j)
            acc[i][j] = (f32x4){0.f, 0.f, 0.f, 0.f};

    int rsw = l16 & 7;

    for (int k0 = 0; k0 < K; k0 += 64) {
        __syncthreads();
#pragma unroll
        for (int i = 0; i < 4; ++i) {
            async16(Al + i * 8 * 64, Ag + (size_t)i * 8 * K + k0);
            async16(Bl + i * 8 * 64, Bg + (size_t)i * 8 * K + k0);
        }
        __syncthreads();

#pragma unroll
        for (int ks = 0; ks < 2; ++ks) {
            int chunk = ((ks << 2) | quad) ^ rsw;
            bf16x8 af[4], bfr[4];
#pragma unroll
            for (int mi = 0; mi < 4; ++mi)
                af[mi]  = *(const bf16x8*)&As[(wm + mi * 16 + l16) * 64 + chunk * 8];
#pragma unroll
            for (int ni = 0; ni < 4; ++ni)
                bfr[ni] = *(const bf16x8*)&Bs[(wn + ni * 16 + l16) * 64 + chunk * 8];
#pragma unroll
            for (int mi = 0; mi < 4; ++mi)
#pragma unroll
                for (int ni = 0; ni < 4; ++ni)
                    acc[mi][ni] = __builtin_amdgcn_mfma_f32_16x16x32_bf16(
                        af[mi], bfr[ni], acc[mi][ni], 0, 0, 0);
        }
    }

    // C/D layout: col = l16, row = quad*4 + r
    if (vt_mode) {
        u16* C = (u16*)C_;
#pragma unroll
        for (int mi = 0; mi < 4; ++mi)
#pragma unroll
            for (int ni = 0; ni < 4; ++ni) {
                size_t m = bm + wm + mi * 16 + quad * 4;   // + r = kv rows
                size_t n = bn + wn + ni * 16 + l16;
                size_t bb = m >> 11, kv = m & 2047;
                size_t hh = n >> 6,  d  = n & 63;
                u16 t4[4];
#pragma unroll
                for (int r = 0; r < 4; ++r) t4[r] = f2bf(acc[mi][ni][r]);
                *(uint2*)&C[((bb * 16 + hh) * 64 + d) * 2048 + kv] = *(const uint2*)t4;
            }
    } else {
#pragma unroll
        for (int mi = 0; mi < 4; ++mi)
#pragma unroll
            for (int ni = 0; ni < 4; ++ni)
#pragma unroll
                for (int r = 0; r < 4; ++r) {
                    size_t row = bm + wm + mi * 16 + quad * 4 + r;
                    size_t col = bn + wn + ni * 16 + l16;
                    float val = acc[mi][ni][r] * cscale;
                    if (c_bf16) ((u16*)C_)[row * N + col]   = f2bf(val);
                    else        ((float*)C_)[row * N + col] = val;
                }
    }
}

// ---------------------------------------------------------------- Attention
__global__ __launch_bounds__(256) void attn_kernel(const u16* __restrict__ qg,
                                                   const u16* __restrict__ kg,
                                                   const u16* __restrict__ vtg,
                                                   const u8* __restrict__ masku,
                                                   u16* __restrict__ og) {
    __shared__ u16 Qs[64][72];
    __shared__ u16 Ks[64][72];
    __shared__ u16 Vst[64][72];
    __shared__ u16 Ps[4][16][72];

    const int NQc = 1024, NKVc = 2048, HD = 1024;
    int bid = blockIdx.x;
    int qt = bid & 15;
    int h  = (bid >> 4) & 15;
    int b  = bid >> 8;

    int tid  = threadIdx.x;
    int wave = tid >> 6, lane = tid & 63;
    int quad = lane >> 4, l16 = lane & 15;
    int q0 = qt * 64;

#pragma unroll
    for (int i = 0; i < 2; ++i) {
        int idx = tid + i * 256;
        int row = idx >> 3;
        int col = (idx & 7) * 8;
        *(uint4*)&Qs[row][col] =
            *(const uint4*)&qg[((size_t)b * NQc + q0 + row) * HD + h * 64 + col];
    }
    __syncthreads();
    bf16x8 aq0 = *(const bf16x8*)&Qs[wave * 16 + l16][quad * 8];
    bf16x8 aq1 = *(const bf16x8*)&Qs[wave * 16 + l16][32 + quad * 8];

    f32x4 O[4], lacc;
#pragma unroll
    for (int nt = 0; nt < 4; ++nt) O[nt] = (f32x4){0.f, 0.f, 0.f, 0.f};
    lacc = (f32x4){0.f, 0.f, 0.f, 0.f};

    bf16x8 bones;
#pragma unroll
    for (int j = 0; j < 8; ++j) bones[j] = (short)0x3F80;

    const u8* mrow = masku + ((size_t)b * NQc + q0 + wave * 16 + l16) * NKVc;

    for (int kv0 = 0; kv0 < NKVc; kv0 += 64) {
        __syncthreads();
#pragma unroll
        for (int i = 0; i < 2; ++i) {
            int idx = tid + i * 256;
            int row = idx >> 3;
            int col = (idx & 7) * 8;
            *(uint4*)&Ks[row][col] =
                *(const uint4*)&kg[((size_t)b * NKVc + kv0 + row) * HD + h * 64 + col];
            *(uint4*)&Vst[row][col] =
                *(const uint4*)&vtg[(((size_t)b * 16 + h) * 64 + row) * NKVc + kv0 + col];
        }
        __syncthreads();

        f32x4 S[4];
#pragma unroll
        for (int nt = 0; nt < 4; ++nt) {
            bf16x8 bk0 = *(const bf16x8*)&Ks[nt * 16 + l16][quad * 8];
            bf16x8 bk1 = *(const bf16x8*)&Ks[nt * 16 + l16][32 + quad * 8];
            f32x4 s = (f32x4){0.f, 0.f, 0.f, 0.f};
            s = __builtin_amdgcn_mfma_f32_16x16x32_bf16(aq0, bk0, s, 0, 0, 0);
            s = __builtin_amdgcn_mfma_f32_16x16x32_bf16(aq1, bk1, s, 0, 0, 0);
            S[nt] = s;
        }

#pragma unroll
        for (int nt = 0; nt < 4; ++nt)
#pragma unroll
            for (int r = 0; r < 4; ++r)
                Ps[wave][quad * 4 + r][nt * 16 + l16] = f2bf(exp2f(S[nt][r]));

        uint2 mv0 = *(const uint2*)&mrow[kv0 + quad * 8];
        uint2 mv1 = *(const uint2*)&mrow[kv0 + 32 + quad * 8];
        uint4 m0, m1;
        m0.x = __builtin_amdgcn_perm(0u, mv0.x, 0x01010000u);
        m0.y = __builtin_amdgcn_perm(0u, mv0.x, 0x03030202u);
        m0.z = __builtin_amdgcn_perm(0u, mv0.y, 0x01010000u);
        m0.w = __builtin_amdgcn_perm(0u, mv0.y, 0x03030202u);
        m1.x = __builtin_amdgcn_perm(0u, mv1.x, 0x01010000u);
        m1.y = __builtin_amdgcn_perm(0u, mv1.x, 0x03030202u);
        m1.z = __builtin_amdgcn_perm(0u, mv1.y, 0x01010000u);
        m1.w = __builtin_amdgcn_perm(0u, mv1.y, 0x03030202u);

        uint4 p0 = *(const uint4*)&Ps[wave][l16][quad * 8];
        uint4 p1 = *(const uint4*)&Ps[wave][l16][32 + quad * 8];
        p0.x &= m0.x; p0.y &= m0.y; p0.z &= m0.z; p0.w &= m0.w;
        p1.x &= m1.x; p1.y &= m1.y; p1.z &= m1.z; p1.w &= m1.w;
        bf16x8 ap0 = *(const bf16x8*)&p0;
        bf16x8 ap1 = *(const bf16x8*)&p1;

        lacc = __builtin_amdgcn_mfma_f32_16x16x32_bf16(ap0, bones, lacc, 0, 0, 0);
        lacc = __builtin_amdgcn_mfma_f32_16x16x32_bf16(ap1, bones, lacc, 0, 0, 0);

#pragma unroll
        for (int nt = 0; nt < 4; ++nt) {
            bf16x8 bv0 = *(const bf16x8*)&Vst[nt * 16 + l16][quad * 8];
            bf16x8 bv1 = *(const bf16x8*)&Vst[nt * 16 + l16][32 + quad * 8];
            O[nt] = __builtin_amdgcn_mfma_f32_16x16x32_bf16(ap0, bv0, O[nt], 0, 0, 0);
            O[nt] = __builtin_amdgcn_mfma_f32_16x16x32_bf16(ap1, bv1, O[nt], 0, 0, 0);
        }
    }

    float inv[4];
#pragma unroll
    for (int r = 0; r < 4; ++r) inv[r] = 1.0f / lacc[r];
#pragma unroll
    for (int nt = 0; nt < 4; ++nt)
#pragma unroll
        for (int r = 0; r < 4; ++r) {
            int qrow = q0 + wave * 16 + quad * 4 + r;
            int col  = h * 64 + nt * 16 + l16;
            og[((size_t)b * NQc + qrow) * HD + col] = f2bf(O[nt][r] * inv[r]);
        }
}

// ---------------------------------------------------------------- launch
extern "C" void kernel_launch(void* const* d_in, const int* in_sizes, int n_in,
                              void* d_out, int out_size, void* d_ws, size_t ws_size,
                              hipStream_t stream) {
    const void* x     = d_in[0];
    const void* key   = d_in[1];
    const void* value = d_in[2];
    const int*  mask  = (const int*)d_in[3];
    const void* Wq    = d_in[4];
    const void* Wk    = d_in[5];
    const void* Wv    = d_in[6];
    const void* Wo    = d_in[7];
    const void* gamma = d_in[8];
    const void* beta  = d_in[9];

    // ws layout (65 MB), time-multiplexed:
    //  @1  xn [8MB] -> mask_u8 after Q-GEMM
    //  @9  kb [16MB] -> q [8MB] @9 + ao [8MB] @17
    //  @25 vb [16MB] -> k [16MB]
    //  @41 vT [16MB]
    //  @57..65 Wqt/Wkt/Wvt/Wot [2MB each]
    char* ws = (char*)d_ws;
    int* flag = (int*)(ws);
    u16* xn  = (u16*)(ws + ( 1ull << 20));
    u8*  mu8 = (u8*) (ws + ( 1ull << 20));
    u16* q   = (u16*)(ws + ( 9ull << 20));
    u16* kb  = (u16*)(ws + ( 9ull << 20));
    u16* ao  = (u16*)(ws + (17ull << 20));
    u16* k   = (u16*)(ws + (25ull << 20));
    u16* vb  = (u16*)(ws + (25ull << 20));
    u16* vT  = (u16*)(ws + (41ull << 20));
    u16* Wqt = (u16*)(ws + (57ull << 20));
    u16* Wkt = (u16*)(ws + (59ull << 20));
    u16* Wvt = (u16*)(ws + (61ull << 20));
    u16* Wot = (u16*)(ws + (63ull << 20));

    const float QSCALE = 0.125f * 1.44269504f;   // d^-0.5 * log2(e) for exp2 softmax

    detect_dtype<<<1, 256, 0, stream>>>((const u32*)x, flag);

    ln_kernel<<<4096, 256, 0, stream>>>(x, gamma, beta, xn, flag);

    dim3 tg(16, 16);
    transpose64<<<tg, 256, 0, stream>>>(Wq, Wqt, 1024, 1024, flag);
    transpose64<<<tg, 256, 0, stream>>>(Wk, Wkt, 1024, 1024, flag);
    transpose64<<<tg, 256, 0, stream>>>(Wv, Wvt, 1024, 1024, flag);
    transpose64<<<tg, 256, 0, stream>>>(Wo, Wot, 1024, 1024, flag);

    conv_bf16<<<4096, 256, 0, stream>>>(key,   kb, flag);
    conv_bf16<<<4096, 256, 0, stream>>>(value, vb, flag);

    gemm128<<<dim3(8, 64), 256, 0, stream>>>(vb, Wvt, vT, 8192, 1024, 1024, flag, 0, 1.0f, 1);
    gemm128<<<dim3(8, 64), 256, 0, stream>>>(kb, Wkt, k,  8192, 1024, 1024, flag, 0, 1.0f, 0);
    gemm128<<<dim3(8, 32), 256, 0, stream>>>(xn, Wqt, q,  4096, 1024, 1024, flag, 0, QSCALE, 0);

    mask_pack<<<2048, 256, 0, stream>>>(mask, mu8);

    attn_kernel<<<1024, 256, 0, stream>>>(q, k, vT, mu8, ao);

    gemm128<<<dim3(8, 32), 256, 0, stream>>>(ao, Wot, d_out, 4096, 1024, 1024, flag, 1, 1.0f, 0);
}

// Round 6
// 402.597 us; speedup vs baseline: 2.3747x; 1.0202x over previous
//
#include <hip/hip_runtime.h>

typedef unsigned short u16;
typedef unsigned int u32;
typedef unsigned char u8;

typedef __attribute__((ext_vector_type(8))) short bf16x8;
typedef __attribute__((ext_vector_type(4))) short bf16x4;
typedef __attribute__((ext_vector_type(4))) float f32x4;

__device__ __forceinline__ float bf2f(u16 u) {
    union { u32 i; float f; } v; v.i = ((u32)u) << 16; return v.f;
}
__device__ __forceinline__ u16 f2bf(float f) {
    union { float f; u32 i; } v; v.f = f;
    u32 r = v.i + 0x7fffu + ((v.i >> 16) & 1u);
    return (u16)(r >> 16);
}
// pack two f32 -> bf16x2 in one u32 (low = a, high = b)
__device__ __forceinline__ u32 pkbf(float a, float b) {
#if __has_builtin(__builtin_amdgcn_cvt_pk_bf16_f32)
    auto r = __builtin_amdgcn_cvt_pk_bf16_f32(a, b);
    u32 u; __builtin_memcpy(&u, &r, 4); return u;
#else
    return (u32)f2bf(a) | ((u32)f2bf(b) << 16);
#endif
}

// async global->LDS, 16B per lane; lds must be wave-uniform (lane*16 added by HW)
__device__ __forceinline__ void async16(u16* lds, const u16* g) {
    __builtin_amdgcn_global_load_lds(
        (const __attribute__((address_space(1))) void*)g,
        (__attribute__((address_space(3))) void*)lds, 16, 0, 0);
}

// ------------------------------------------------------------- dtype detect
__global__ __launch_bounds__(256) void detect_dtype(const u32* __restrict__ x,
                                                    int* __restrict__ flag) {
    int tid = threadIdx.x;
    int hits = 0;
    for (int i = 0; i < 4; ++i) {
        u32 w = x[tid * 4 + i];
        u32 e = (w >> 7) & 0xFFu;
        hits += (e >= 110u && e <= 131u) ? 1 : 0;
    }
    for (int off = 1; off < 64; off <<= 1) hits += __shfl_xor(hits, off, 64);
    __shared__ int red[4];
    int wave = tid >> 6, lane = tid & 63;
    if (lane == 0) red[wave] = hits;
    __syncthreads();
    if (tid == 0) flag[0] = (red[0] + red[1] + red[2] + red[3] > 512) ? 1 : 0;
}

// ------------------------------------------------------------- convert pass
__global__ __launch_bounds__(256) void conv_bf16(const void* __restrict__ src,
                                                 u16* __restrict__ dst,
                                                 const int* __restrict__ flagp) {
    int flag = *flagp;
    size_t i = (size_t)blockIdx.x * 256 + threadIdx.x;
    if (flag) {
        ((uint4*)dst)[i] = ((const uint4*)src)[i];
    } else {
        const float4* s = (const float4*)src + i * 2;
        float4 f0 = s[0], f1 = s[1];
        u16 t[8];
        t[0] = f2bf(f0.x); t[1] = f2bf(f0.y); t[2] = f2bf(f0.z); t[3] = f2bf(f0.w);
        t[4] = f2bf(f1.x); t[5] = f2bf(f1.y); t[6] = f2bf(f1.z); t[7] = f2bf(f1.w);
        ((uint4*)dst)[i] = *(const uint4*)t;
    }
}

// ------------------------------------------------------------- mask pack
__global__ __launch_bounds__(256) void mask_pack(const int* __restrict__ m,
                                                 u8* __restrict__ o) {
    size_t i = (size_t)blockIdx.x * 256 + threadIdx.x;
    const int4* mp = (const int4*)m + i * 4;
    uint4 out;
    u32* op = (u32*)&out;
    for (int j = 0; j < 4; ++j) {
        int4 a = mp[j];
        op[j] = (a.x == 0 ? 0xFFu : 0u) | (a.y == 0 ? 0xFF00u : 0u) |
                (a.z == 0 ? 0xFF0000u : 0u) | (a.w == 0 ? 0xFF000000u : 0u);
    }
    ((uint4*)o)[i] = out;
}

// ---------------------------------------------------------------- LayerNorm
__global__ __launch_bounds__(256) void ln_kernel(const void* __restrict__ x_,
                                                 const void* __restrict__ g_,
                                                 const void* __restrict__ b_,
                                                 u16* __restrict__ out,
                                                 const int* __restrict__ flagp) {
    int flag = *flagp;
    int row = blockIdx.x;
    int tid = threadIdx.x;
    float v[4];
    if (flag) {
        const u16* xr = (const u16*)x_ + (size_t)row * 1024;
        uint2 d = *(const uint2*)&xr[tid * 4];
        v[0] = bf2f((u16)(d.x & 0xffff));
        v[1] = bf2f((u16)(d.x >> 16));
        v[2] = bf2f((u16)(d.y & 0xffff));
        v[3] = bf2f((u16)(d.y >> 16));
    } else {
        const float* xr = (const float*)x_ + (size_t)row * 1024;
        float4 d = *(const float4*)&xr[tid * 4];
        v[0] = d.x; v[1] = d.y; v[2] = d.z; v[3] = d.w;
    }
    float s  = v[0] + v[1] + v[2] + v[3];
    float ss = v[0]*v[0] + v[1]*v[1] + v[2]*v[2] + v[3]*v[3];
    for (int off = 1; off < 64; off <<= 1) {
        s  += __shfl_xor(s,  off, 64);
        ss += __shfl_xor(ss, off, 64);
    }
    __shared__ float red[8];
    int wave = tid >> 6, lane = tid & 63;
    if (lane == 0) { red[wave] = s; red[4 + wave] = ss; }
    __syncthreads();
    s  = red[0] + red[1] + red[2] + red[3];
    ss = red[4] + red[5] + red[6] + red[7];
    float mu   = s * (1.0f / 1024.0f);
    float var  = ss * (1.0f / 1024.0f) - mu * mu;
    float rstd = rsqrtf(var + 1e-5f);
    u16 r01[4];
    for (int j = 0; j < 4; ++j) {
        float g, bb;
        if (flag) { g = bf2f(((const u16*)g_)[tid * 4 + j]); bb = bf2f(((const u16*)b_)[tid * 4 + j]); }
        else      { g = ((const float*)g_)[tid * 4 + j];     bb = ((const float*)b_)[tid * 4 + j]; }
        r01[j] = f2bf((v[j] - mu) * rstd * g + bb);
    }
    uint2 o;
    o.x = (u32)r01[0] | ((u32)r01[1] << 16);
    o.y = (u32)r01[2] | ((u32)r01[3] << 16);
    *(uint2*)&out[(size_t)row * 1024 + tid * 4] = o;
}

// ---------------------------------------------------------------- Transpose
__global__ __launch_bounds__(256) void transpose64(const void* __restrict__ src_,
                                                   u16* __restrict__ dst,
                                                   int rows, int cols,
                                                   const int* __restrict__ flagp) {
    __shared__ u16 t[64][65];
    int flag = *flagp;
    int bx = blockIdx.x * 64;
    int by = blockIdx.y * 64;
    int tid = threadIdx.x;
    for (int i = 0; i < 16; ++i) {
        int r = i * 4 + (tid >> 6);
        int c = tid & 63;
        size_t idx = (size_t)(by + r) * cols + bx + c;
        t[r][c] = flag ? ((const u16*)src_)[idx] : f2bf(((const float*)src_)[idx]);
    }
    __syncthreads();
    for (int i = 0; i < 16; ++i) {
        int r = i * 4 + (tid >> 6);
        int c = tid & 63;
        dst[(size_t)(bx + r) * rows + by + c] = t[c][r];
    }
}

// ------------------------------------------------------- GEMM 128x128 (B^T)
__global__ __launch_bounds__(256, 2) void gemm128(const u16* __restrict__ A,
                                                  const u16* __restrict__ Bt,
                                                  void* __restrict__ C_,
                                                  int M, int N, int K,
                                                  const int* __restrict__ flagp,
                                                  int c_flagged, float cscale,
                                                  int vt_mode) {
    __shared__ u16 As[128 * 64];
    __shared__ u16 Bs[128 * 64];
    int flag = *flagp;
    bool c_bf16 = c_flagged ? (flag != 0) : true;

    int tid  = threadIdx.x;
    int wave = tid >> 6, lane = tid & 63;
    int quad = lane >> 4, l16 = lane & 15;
    size_t bm = (size_t)blockIdx.y * 128;
    size_t bn = (size_t)blockIdx.x * 128;
    int wm = (wave >> 1) * 64, wn = (wave & 1) * 64;

    int lr  = lane >> 3;
    int csw = (lane & 7) ^ lr;
    const u16* Ag = A  + (bm + wave * 32 + lr) * (size_t)K + csw * 8;
    const u16* Bg = Bt + (bn + wave * 32 + lr) * (size_t)K + csw * 8;
    u16* Al = &As[(wave * 32) * 64];
    u16* Bl = &Bs[(wave * 32) * 64];

    f32x4 acc[4][4];
#pragma unroll
    for (int i = 0; i < 4; ++i)
#pragma unroll
        for (int j = 0; j < 4; ++j)
            acc[i][j] = (f32x4){0.f, 0.f, 0.f, 0.f};

    int rsw = l16 & 7;

    for (int k0 = 0; k0 < K; k0 += 64) {
        __syncthreads();
#pragma unroll
        for (int i = 0; i < 4; ++i) {
            async16(Al + i * 8 * 64, Ag + (size_t)i * 8 * K + k0);
            async16(Bl + i * 8 * 64, Bg + (size_t)i * 8 * K + k0);
        }
        __syncthreads();

#pragma unroll
        for (int ks = 0; ks < 2; ++ks) {
            int chunk = ((ks << 2) | quad) ^ rsw;
            bf16x8 af[4], bfr[4];
#pragma unroll
            for (int mi = 0; mi < 4; ++mi)
                af[mi]  = *(const bf16x8*)&As[(wm + mi * 16 + l16) * 64 + chunk * 8];
#pragma unroll
            for (int ni = 0; ni < 4; ++ni)
                bfr[ni] = *(const bf16x8*)&Bs[(wn + ni * 16 + l16) * 64 + chunk * 8];
#pragma unroll
            for (int mi = 0; mi < 4; ++mi)
#pragma unroll
                for (int ni = 0; ni < 4; ++ni)
                    acc[mi][ni] = __builtin_amdgcn_mfma_f32_16x16x32_bf16(
                        af[mi], bfr[ni], acc[mi][ni], 0, 0, 0);
        }
    }

    if (vt_mode) {
        u16* C = (u16*)C_;
#pragma unroll
        for (int mi = 0; mi < 4; ++mi)
#pragma unroll
            for (int ni = 0; ni < 4; ++ni) {
                size_t m = bm + wm + mi * 16 + quad * 4;
                size_t n = bn + wn + ni * 16 + l16;
                size_t bb = m >> 11, kv = m & 2047;
                size_t hh = n >> 6,  d  = n & 63;
                u16 t4[4];
#pragma unroll
                for (int r = 0; r < 4; ++r) t4[r] = f2bf(acc[mi][ni][r]);
                *(uint2*)&C[((bb * 16 + hh) * 64 + d) * 2048 + kv] = *(const uint2*)t4;
            }
    } else {
#pragma unroll
        for (int mi = 0; mi < 4; ++mi)
#pragma unroll
            for (int ni = 0; ni < 4; ++ni)
#pragma unroll
                for (int r = 0; r < 4; ++r) {
                    size_t row = bm + wm + mi * 16 + quad * 4 + r;
                    size_t col = bn + wn + ni * 16 + l16;
                    float val = acc[mi][ni][r] * cscale;
                    if (c_bf16) ((u16*)C_)[row * N + col]   = f2bf(val);
                    else        ((float*)C_)[row * N + col] = val;
                }
    }
}

// ---------------------------------------------------------------- Attention
// S^T formulation, no P LDS round-trip. Block = (b, h, 64 q-rows), 4 waves x
// 16 q each. S^T = K·Q^T via mfma_16x16x32 (operands swapped vs GEMM): C/D
// layout gives lane q=l16, kv=quad*4+r — which IS the B-operand layout of
// mfma_f32_16x16x16bf16_1k. exp2+mask in-register, pack to bf16x4, feed
// directly into O^T = V^T·P^T (K=16 MFMAs) and l = ones·P^T. No Qs/Ps LDS.
__global__ __launch_bounds__(256) void attn_kernel(const u16* __restrict__ qg,
                                                   const u16* __restrict__ kg,
                                                   const u16* __restrict__ vtg,
                                                   const u8* __restrict__ masku,
                                                   u16* __restrict__ og) {
    __shared__ u16 Ks[64][72];
    __shared__ u16 Vst[64][72];      // [d][kv] staged from vT

    const int NQc = 1024, NKVc = 2048, HD = 1024;
    int bid = blockIdx.x;
    int qt = bid & 15;
    int h  = (bid >> 4) & 15;
    int b  = bid >> 8;

    int tid  = threadIdx.x;
    int wave = tid >> 6, lane = tid & 63;
    int quad = lane >> 4, l16 = lane & 15;
    int q0 = qt * 64;

    // Q fragment (B-operand: n=q=l16, k=d=quad*8+j) straight from global
    const u16* qrow = qg + ((size_t)b * NQc + q0 + wave * 16 + l16) * HD + h * 64;
    bf16x8 aq0 = *(const bf16x8*)&qrow[quad * 8];
    bf16x8 aq1 = *(const bf16x8*)&qrow[32 + quad * 8];

    f32x4 O[4], lacc;
#pragma unroll
    for (int dt = 0; dt < 4; ++dt) O[dt] = (f32x4){0.f, 0.f, 0.f, 0.f};
    lacc = (f32x4){0.f, 0.f, 0.f, 0.f};

    bf16x4 ones4;
#pragma unroll
    for (int j = 0; j < 4; ++j) ones4[j] = (short)0x3F80;

    const u8* mrow = masku + ((size_t)b * NQc + q0 + wave * 16 + l16) * (size_t)NKVc;

    for (int kv0 = 0; kv0 < NKVc; kv0 += 64) {
        __syncthreads();
#pragma unroll
        for (int i = 0; i < 2; ++i) {
            int idx = tid + i * 256;
            int row = idx >> 3;
            int col = (idx & 7) * 8;
            *(uint4*)&Ks[row][col] =
                *(const uint4*)&kg[((size_t)b * NKVc + kv0 + row) * HD + h * 64 + col];
            *(uint4*)&Vst[row][col] =
                *(const uint4*)&vtg[(((size_t)b * 16 + h) * 64 + row) * NKVc + kv0 + col];
        }
        __syncthreads();

        // per nt: S^T tile -> exp2 -> mask -> bf16x4 P^T fragment
        bf16x4 pfr[4];
#pragma unroll
        for (int nt = 0; nt < 4; ++nt) {
            bf16x8 bk0 = *(const bf16x8*)&Ks[nt * 16 + l16][quad * 8];
            bf16x8 bk1 = *(const bf16x8*)&Ks[nt * 16 + l16][32 + quad * 8];
            f32x4 st = (f32x4){0.f, 0.f, 0.f, 0.f};
            st = __builtin_amdgcn_mfma_f32_16x16x32_bf16(bk0, aq0, st, 0, 0, 0);
            st = __builtin_amdgcn_mfma_f32_16x16x32_bf16(bk1, aq1, st, 0, 0, 0);

            u32 mword = *(const u32*)&mrow[kv0 + nt * 16 + quad * 4];
            u32 p01 = pkbf(exp2f(st[0]), exp2f(st[1])) &
                      __builtin_amdgcn_perm(0u, mword, 0x01010000u);
            u32 p23 = pkbf(exp2f(st[2]), exp2f(st[3])) &
                      __builtin_amdgcn_perm(0u, mword, 0x03030202u);
            uint2 pu; pu.x = p01; pu.y = p23;
            pfr[nt] = *(const bf16x4*)&pu;

            // l += 1^T . P^T  (all C rows equal the kv-sum for col q=l16)
            lacc = __builtin_amdgcn_mfma_f32_16x16x16bf16_1k(ones4, pfr[nt], lacc, 0, 0, 0);
        }

        // O^T += V^T . P^T
#pragma unroll
        for (int dt = 0; dt < 4; ++dt)
#pragma unroll
            for (int kvs = 0; kvs < 4; ++kvs) {
                bf16x4 av = *(const bf16x4*)&Vst[dt * 16 + l16][kvs * 16 + quad * 4];
                O[dt] = __builtin_amdgcn_mfma_f32_16x16x16bf16_1k(av, pfr[kvs], O[dt], 0, 0, 0);
            }
    }

    // epilogue: O^T lane holds q=l16, d=dt*16+quad*4+r -> 4 consecutive d
    float inv = 1.0f / lacc[0];
    u16* orow = og + ((size_t)b * NQc + q0 + wave * 16 + l16) * HD + h * 64;
#pragma unroll
    for (int dt = 0; dt < 4; ++dt) {
        u16 t4[4];
#pragma unroll
        for (int r = 0; r < 4; ++r) t4[r] = f2bf(O[dt][r] * inv);
        *(uint2*)&orow[dt * 16 + quad * 4] = *(const uint2*)t4;
    }
}

// ---------------------------------------------------------------- launch
extern "C" void kernel_launch(void* const* d_in, const int* in_sizes, int n_in,
                              void* d_out, int out_size, void* d_ws, size_t ws_size,
                              hipStream_t stream) {
    const void* x     = d_in[0];
    const void* key   = d_in[1];
    const void* value = d_in[2];
    const int*  mask  = (const int*)d_in[3];
    const void* Wq    = d_in[4];
    const void* Wk    = d_in[5];
    const void* Wv    = d_in[6];
    const void* Wo    = d_in[7];
    const void* gamma = d_in[8];
    const void* beta  = d_in[9];

    // ws layout (65 MB), time-multiplexed:
    //  @1  xn [8MB] -> mask_u8 after Q-GEMM
    //  @9  kb [16MB] -> q [8MB] @9 + ao [8MB] @17
    //  @25 vb [16MB] -> k [16MB]
    //  @41 vT [16MB]
    //  @57..65 Wqt/Wkt/Wvt/Wot [2MB each]
    char* ws = (char*)d_ws;
    int* flag = (int*)(ws);
    u16* xn  = (u16*)(ws + ( 1ull << 20));
    u8*  mu8 = (u8*) (ws + ( 1ull << 20));
    u16* q   = (u16*)(ws + ( 9ull << 20));
    u16* kb  = (u16*)(ws + ( 9ull << 20));
    u16* ao  = (u16*)(ws + (17ull << 20));
    u16* k   = (u16*)(ws + (25ull << 20));
    u16* vb  = (u16*)(ws + (25ull << 20));
    u16* vT  = (u16*)(ws + (41ull << 20));
    u16* Wqt = (u16*)(ws + (57ull << 20));
    u16* Wkt = (u16*)(ws + (59ull << 20));
    u16* Wvt = (u16*)(ws + (61ull << 20));
    u16* Wot = (u16*)(ws + (63ull << 20));

    const float QSCALE = 0.125f * 1.44269504f;   // d^-0.5 * log2(e) for exp2 softmax

    detect_dtype<<<1, 256, 0, stream>>>((const u32*)x, flag);

    ln_kernel<<<4096, 256, 0, stream>>>(x, gamma, beta, xn, flag);

    dim3 tg(16, 16);
    transpose64<<<tg, 256, 0, stream>>>(Wq, Wqt, 1024, 1024, flag);
    transpose64<<<tg, 256, 0, stream>>>(Wk, Wkt, 1024, 1024, flag);
    transpose64<<<tg, 256, 0, stream>>>(Wv, Wvt, 1024, 1024, flag);
    transpose64<<<tg, 256, 0, stream>>>(Wo, Wot, 1024, 1024, flag);

    conv_bf16<<<4096, 256, 0, stream>>>(key,   kb, flag);
    conv_bf16<<<4096, 256, 0, stream>>>(value, vb, flag);

    gemm128<<<dim3(8, 64), 256, 0, stream>>>(vb, Wvt, vT, 8192, 1024, 1024, flag, 0, 1.0f, 1);
    gemm128<<<dim3(8, 64), 256, 0, stream>>>(kb, Wkt, k,  8192, 1024, 1024, flag, 0, 1.0f, 0);
    gemm128<<<dim3(8, 32), 256, 0, stream>>>(xn, Wqt, q,  4096, 1024, 1024, flag, 0, QSCALE, 0);

    mask_pack<<<2048, 256, 0, stream>>>(mask, mu8);

    attn_kernel<<<1024, 256, 0, stream>>>(q, k, vT, mu8, ao);

    gemm128<<<dim3(8, 32), 256, 0, stream>>>(ao, Wot, d_out, 4096, 1024, 1024, flag, 1, 1.0f, 0);
}

// Round 7
// 388.961 us; speedup vs baseline: 2.4580x; 1.0351x over previous
//
#include <hip/hip_runtime.h>

typedef unsigned short u16;
typedef unsigned int u32;
typedef unsigned char u8;

typedef __attribute__((ext_vector_type(8))) short bf16x8;
typedef __attribute__((ext_vector_type(4))) short bf16x4;
typedef __attribute__((ext_vector_type(4))) float f32x4;

__device__ __forceinline__ float bf2f(u16 u) {
    union { u32 i; float f; } v; v.i = ((u32)u) << 16; return v.f;
}
__device__ __forceinline__ u16 f2bf(float f) {
    union { float f; u32 i; } v; v.f = f;
    u32 r = v.i + 0x7fffu + ((v.i >> 16) & 1u);
    return (u16)(r >> 16);
}
// pack two f32 -> bf16x2 in one u32 (low = a, high = b)
__device__ __forceinline__ u32 pkbf(float a, float b) {
#if __has_builtin(__builtin_amdgcn_cvt_pk_bf16_f32)
    auto r = __builtin_amdgcn_cvt_pk_bf16_f32(a, b);
    u32 u; __builtin_memcpy(&u, &r, 4); return u;
#else
    return (u32)f2bf(a) | ((u32)f2bf(b) << 16);
#endif
}

// async global->LDS, 16B per lane; lds must be wave-uniform (lane*16 added by HW)
__device__ __forceinline__ void async16(u16* lds, const u16* g) {
    __builtin_amdgcn_global_load_lds(
        (const __attribute__((address_space(1))) void*)g,
        (__attribute__((address_space(3))) void*)lds, 16, 0, 0);
}

// ------------------------------------------------------------- dtype detect
__global__ __launch_bounds__(256) void detect_dtype(const u32* __restrict__ x,
                                                    int* __restrict__ flag) {
    int tid = threadIdx.x;
    int hits = 0;
    for (int i = 0; i < 4; ++i) {
        u32 w = x[tid * 4 + i];
        u32 e = (w >> 7) & 0xFFu;
        hits += (e >= 110u && e <= 131u) ? 1 : 0;
    }
    for (int off = 1; off < 64; off <<= 1) hits += __shfl_xor(hits, off, 64);
    __shared__ int red[4];
    int wave = tid >> 6, lane = tid & 63;
    if (lane == 0) red[wave] = hits;
    __syncthreads();
    if (tid == 0) flag[0] = (red[0] + red[1] + red[2] + red[3] > 512) ? 1 : 0;
}

// ------------------------------------------------------------- convert pass
__global__ __launch_bounds__(256) void conv_bf16(const void* __restrict__ src,
                                                 u16* __restrict__ dst,
                                                 const int* __restrict__ flagp) {
    int flag = *flagp;
    size_t i = (size_t)blockIdx.x * 256 + threadIdx.x;
    if (flag) {
        ((uint4*)dst)[i] = ((const uint4*)src)[i];
    } else {
        const float4* s = (const float4*)src + i * 2;
        float4 f0 = s[0], f1 = s[1];
        u16 t[8];
        t[0] = f2bf(f0.x); t[1] = f2bf(f0.y); t[2] = f2bf(f0.z); t[3] = f2bf(f0.w);
        t[4] = f2bf(f1.x); t[5] = f2bf(f1.y); t[6] = f2bf(f1.z); t[7] = f2bf(f1.w);
        ((uint4*)dst)[i] = *(const uint4*)t;
    }
}

// ------------------------------------------------------------- mask pack
__global__ __launch_bounds__(256) void mask_pack(const int* __restrict__ m,
                                                 u8* __restrict__ o) {
    size_t i = (size_t)blockIdx.x * 256 + threadIdx.x;
    const int4* mp = (const int4*)m + i * 4;
    uint4 out;
    u32* op = (u32*)&out;
    for (int j = 0; j < 4; ++j) {
        int4 a = mp[j];
        op[j] = (a.x == 0 ? 0xFFu : 0u) | (a.y == 0 ? 0xFF00u : 0u) |
                (a.z == 0 ? 0xFF0000u : 0u) | (a.w == 0 ? 0xFF000000u : 0u);
    }
    ((uint4*)o)[i] = out;
}

// ---------------------------------------------------------------- LayerNorm
__global__ __launch_bounds__(256) void ln_kernel(const void* __restrict__ x_,
                                                 const void* __restrict__ g_,
                                                 const void* __restrict__ b_,
                                                 u16* __restrict__ out,
                                                 const int* __restrict__ flagp) {
    int flag = *flagp;
    int row = blockIdx.x;
    int tid = threadIdx.x;
    float v[4];
    if (flag) {
        const u16* xr = (const u16*)x_ + (size_t)row * 1024;
        uint2 d = *(const uint2*)&xr[tid * 4];
        v[0] = bf2f((u16)(d.x & 0xffff));
        v[1] = bf2f((u16)(d.x >> 16));
        v[2] = bf2f((u16)(d.y & 0xffff));
        v[3] = bf2f((u16)(d.y >> 16));
    } else {
        const float* xr = (const float*)x_ + (size_t)row * 1024;
        float4 d = *(const float4*)&xr[tid * 4];
        v[0] = d.x; v[1] = d.y; v[2] = d.z; v[3] = d.w;
    }
    float s  = v[0] + v[1] + v[2] + v[3];
    float ss = v[0]*v[0] + v[1]*v[1] + v[2]*v[2] + v[3]*v[3];
    for (int off = 1; off < 64; off <<= 1) {
        s  += __shfl_xor(s,  off, 64);
        ss += __shfl_xor(ss, off, 64);
    }
    __shared__ float red[8];
    int wave = tid >> 6, lane = tid & 63;
    if (lane == 0) { red[wave] = s; red[4 + wave] = ss; }
    __syncthreads();
    s  = red[0] + red[1] + red[2] + red[3];
    ss = red[4] + red[5] + red[6] + red[7];
    float mu   = s * (1.0f / 1024.0f);
    float var  = ss * (1.0f / 1024.0f) - mu * mu;
    float rstd = rsqrtf(var + 1e-5f);
    u16 r01[4];
    for (int j = 0; j < 4; ++j) {
        float g, bb;
        if (flag) { g = bf2f(((const u16*)g_)[tid * 4 + j]); bb = bf2f(((const u16*)b_)[tid * 4 + j]); }
        else      { g = ((const float*)g_)[tid * 4 + j];     bb = ((const float*)b_)[tid * 4 + j]; }
        r01[j] = f2bf((v[j] - mu) * rstd * g + bb);
    }
    uint2 o;
    o.x = (u32)r01[0] | ((u32)r01[1] << 16);
    o.y = (u32)r01[2] | ((u32)r01[3] << 16);
    *(uint2*)&out[(size_t)row * 1024 + tid * 4] = o;
}

// ---------------------------------------------------------------- Transpose
__global__ __launch_bounds__(256) void transpose64(const void* __restrict__ src_,
                                                   u16* __restrict__ dst,
                                                   int rows, int cols,
                                                   const int* __restrict__ flagp) {
    __shared__ u16 t[64][65];
    int flag = *flagp;
    int bx = blockIdx.x * 64;
    int by = blockIdx.y * 64;
    int tid = threadIdx.x;
    for (int i = 0; i < 16; ++i) {
        int r = i * 4 + (tid >> 6);
        int c = tid & 63;
        size_t idx = (size_t)(by + r) * cols + bx + c;
        t[r][c] = flag ? ((const u16*)src_)[idx] : f2bf(((const float*)src_)[idx]);
    }
    __syncthreads();
    for (int i = 0; i < 16; ++i) {
        int r = i * 4 + (tid >> 6);
        int c = tid & 63;
        dst[(size_t)(bx + r) * rows + by + c] = t[c][r];
    }
}

// ------------------------------------------------------- GEMM 128x128 (B^T)
// 1-D grid, XCD-grouped: the 8 bn-siblings of each bm-row map to one XCD
// (hardware round-robins xcd = blockIdx.x % 8), so the shared A-tile (256 KB)
// and B (2 MB) stay in that XCD's L2. mdiv = (M/128)/8.
__global__ __launch_bounds__(256, 2) void gemm128(const u16* __restrict__ A,
                                                  const u16* __restrict__ Bt,
                                                  void* __restrict__ C_,
                                                  int M, int N, int K,
                                                  const int* __restrict__ flagp,
                                                  int c_flagged, float cscale,
                                                  int vt_mode, int mdiv) {
    __shared__ u16 As[128 * 64];
    __shared__ u16 Bs[128 * 64];
    int flag = *flagp;
    bool c_bf16 = c_flagged ? (flag != 0) : true;

    int id  = blockIdx.x;
    int j   = id >> 3;
    int gy  = (id & 7) + 8 * (j % mdiv);
    int bnt = j / mdiv;

    int tid  = threadIdx.x;
    int wave = tid >> 6, lane = tid & 63;
    int quad = lane >> 4, l16 = lane & 15;
    size_t bm = (size_t)gy * 128;
    size_t bn = (size_t)bnt * 128;
    int wm = (wave >> 1) * 64, wn = (wave & 1) * 64;

    int lr  = lane >> 3;
    int csw = (lane & 7) ^ lr;
    const u16* Ag = A  + (bm + wave * 32 + lr) * (size_t)K + csw * 8;
    const u16* Bg = Bt + (bn + wave * 32 + lr) * (size_t)K + csw * 8;
    u16* Al = &As[(wave * 32) * 64];
    u16* Bl = &Bs[(wave * 32) * 64];

    f32x4 acc[4][4];
#pragma unroll
    for (int i = 0; i < 4; ++i)
#pragma unroll
        for (int jj = 0; jj < 4; ++jj)
            acc[i][jj] = (f32x4){0.f, 0.f, 0.f, 0.f};

    int rsw = l16 & 7;

    for (int k0 = 0; k0 < K; k0 += 64) {
        __syncthreads();
#pragma unroll
        for (int i = 0; i < 4; ++i) {
            async16(Al + i * 8 * 64, Ag + (size_t)i * 8 * K + k0);
            async16(Bl + i * 8 * 64, Bg + (size_t)i * 8 * K + k0);
        }
        __syncthreads();

#pragma unroll
        for (int ks = 0; ks < 2; ++ks) {
            int chunk = ((ks << 2) | quad) ^ rsw;
            bf16x8 af[4], bfr[4];
#pragma unroll
            for (int mi = 0; mi < 4; ++mi)
                af[mi]  = *(const bf16x8*)&As[(wm + mi * 16 + l16) * 64 + chunk * 8];
#pragma unroll
            for (int ni = 0; ni < 4; ++ni)
                bfr[ni] = *(const bf16x8*)&Bs[(wn + ni * 16 + l16) * 64 + chunk * 8];
#pragma unroll
            for (int mi = 0; mi < 4; ++mi)
#pragma unroll
                for (int ni = 0; ni < 4; ++ni)
                    acc[mi][ni] = __builtin_amdgcn_mfma_f32_16x16x32_bf16(
                        af[mi], bfr[ni], acc[mi][ni], 0, 0, 0);
        }
    }

    if (vt_mode) {
        u16* C = (u16*)C_;
#pragma unroll
        for (int mi = 0; mi < 4; ++mi)
#pragma unroll
            for (int ni = 0; ni < 4; ++ni) {
                size_t m = bm + wm + mi * 16 + quad * 4;
                size_t n = bn + wn + ni * 16 + l16;
                size_t bb = m >> 11, kv = m & 2047;
                size_t hh = n >> 6,  d  = n & 63;
                u16 t4[4];
#pragma unroll
                for (int r = 0; r < 4; ++r) t4[r] = f2bf(acc[mi][ni][r]);
                *(uint2*)&C[((bb * 16 + hh) * 64 + d) * 2048 + kv] = *(const uint2*)t4;
            }
    } else {
#pragma unroll
        for (int mi = 0; mi < 4; ++mi)
#pragma unroll
            for (int ni = 0; ni < 4; ++ni)
#pragma unroll
                for (int r = 0; r < 4; ++r) {
                    size_t row = bm + wm + mi * 16 + quad * 4 + r;
                    size_t col = bn + wn + ni * 16 + l16;
                    float val = acc[mi][ni][r] * cscale;
                    if (c_bf16) ((u16*)C_)[row * N + col]   = f2bf(val);
                    else        ((float*)C_)[row * N + col] = val;
                }
    }
}

// ---------------------------------------------------------------- Attention
// S^T formulation (round 6) + XCD-grouped blocks + async XOR-swizzled staging.
// Block remap: all 16 qt-tiles of one (b,h) share an XCD -> K/V L2-resident.
// Ks/Vst: flat [64*64], 16B chunk c of row r stored at chunk c^(r&7), staged
// via global_load_lds (2 calls/matrix). Ks reads are the GEMM's proven
// 0-conflict b128 pattern; Vst b64 reads become 2-way within lane quarters.
__global__ __launch_bounds__(256) void attn_kernel(const u16* __restrict__ qg,
                                                   const u16* __restrict__ kg,
                                                   const u16* __restrict__ vtg,
                                                   const u8* __restrict__ masku,
                                                   u16* __restrict__ og) {
    __shared__ u16 Ks[64 * 64];
    __shared__ u16 Vst[64 * 64];     // [d][kv], swizzled

    const int NQc = 1024, NKVc = 2048, HD = 1024;
    int id = blockIdx.x;
    int j  = id >> 3;
    int qt = j >> 3;                       // [0,16)
    int g  = (id & 7) + ((j & 7) << 3);    // [0,64) (b,h) group; xcd = id&7
    int h  = g & 15;
    int b  = g >> 4;

    int tid  = threadIdx.x;
    int wave = tid >> 6, lane = tid & 63;
    int quad = lane >> 4, l16 = lane & 15;
    int q0 = qt * 64;

    // Q fragment (B-operand: n=q=l16, k=d=quad*8+j) straight from global
    const u16* qrow = qg + ((size_t)b * NQc + q0 + wave * 16 + l16) * HD + h * 64;
    bf16x8 aq0 = *(const bf16x8*)&qrow[quad * 8];
    bf16x8 aq1 = *(const bf16x8*)&qrow[32 + quad * 8];

    // staging source addressing (per lane): row lr in 8-row group, chunk swizzle
    int lr  = lane >> 3;                   // [0,8)
    int csw = (lane & 7) ^ lr;             // source 16B chunk for phys lane&7
    const u16* kbase = kg  + ((size_t)b * NKVc + wave * 8 + lr) * HD + h * 64 + csw * 8;
    const u16* vbase = vtg + (((size_t)b * 16 + h) * 64 + wave * 8 + lr) * (size_t)NKVc + csw * 8;
    u16* kl = Ks  + (wave * 8) * 64;
    u16* vl = Vst + (wave * 8) * 64;

    f32x4 O[4], lacc;
#pragma unroll
    for (int dt = 0; dt < 4; ++dt) O[dt] = (f32x4){0.f, 0.f, 0.f, 0.f};
    lacc = (f32x4){0.f, 0.f, 0.f, 0.f};

    bf16x4 ones4;
#pragma unroll
    for (int jj = 0; jj < 4; ++jj) ones4[jj] = (short)0x3F80;

    const u8* mrow = masku + ((size_t)b * NQc + q0 + wave * 16 + l16) * (size_t)NKVc;

    int l7 = l16 & 7;

    for (int kv0 = 0; kv0 < NKVc; kv0 += 64) {
        __syncthreads();
#pragma unroll
        for (int i = 0; i < 2; ++i) {
            // K rows kv0+i*32+wave*8+lr ; V (d-rows) i*32+wave*8+lr, cols kv0
            async16(kl + i * 32 * 64, kbase + ((size_t)kv0 + i * 32) * HD);
            async16(vl + i * 32 * 64, vbase + (size_t)(i * 32) * NKVc + kv0);
        }
        __syncthreads();

        // per nt: S^T tile -> exp2 -> mask -> bf16x4 P^T fragment
        bf16x4 pfr[4];
#pragma unroll
        for (int nt = 0; nt < 4; ++nt) {
            const u16* krow = Ks + (nt * 16 + l16) * 64;
            bf16x8 bk0 = *(const bf16x8*)&krow[(quad ^ l7) * 8];
            bf16x8 bk1 = *(const bf16x8*)&krow[((4 + quad) ^ l7) * 8];
            f32x4 st = (f32x4){0.f, 0.f, 0.f, 0.f};
            st = __builtin_amdgcn_mfma_f32_16x16x32_bf16(bk0, aq0, st, 0, 0, 0);
            st = __builtin_amdgcn_mfma_f32_16x16x32_bf16(bk1, aq1, st, 0, 0, 0);

            u32 mword = *(const u32*)&mrow[kv0 + nt * 16 + quad * 4];
            u32 p01 = pkbf(exp2f(st[0]), exp2f(st[1])) &
                      __builtin_amdgcn_perm(0u, mword, 0x01010000u);
            u32 p23 = pkbf(exp2f(st[2]), exp2f(st[3])) &
                      __builtin_amdgcn_perm(0u, mword, 0x03030202u);
            uint2 pu; pu.x = p01; pu.y = p23;
            pfr[nt] = *(const bf16x4*)&pu;

            lacc = __builtin_amdgcn_mfma_f32_16x16x16bf16_1k(ones4, pfr[nt], lacc, 0, 0, 0);
        }

        // O^T += V^T . P^T   (A-frag: d-row = dt*16+l16, kv = kvs*16+quad*4)
#pragma unroll
        for (int dt = 0; dt < 4; ++dt) {
            const u16* vrow = Vst + (dt * 16 + l16) * 64;
#pragma unroll
            for (int kvs = 0; kvs < 4; ++kvs) {
                int gran = ((kvs << 1) | (quad >> 1)) ^ l7;   // 16B granule (2 per read-half)
                bf16x4 av = *(const bf16x4*)&vrow[gran * 8 + (quad & 1) * 4];
                O[dt] = __builtin_amdgcn_mfma_f32_16x16x16bf16_1k(av, pfr[kvs], O[dt], 0, 0, 0);
            }
        }
    }

    // epilogue: O^T lane holds q=l16, d=dt*16+quad*4+r -> 4 consecutive d
    float inv = 1.0f / lacc[0];
    u16* orow = og + ((size_t)b * NQc + q0 + wave * 16 + l16) * HD + h * 64;
#pragma unroll
    for (int dt = 0; dt < 4; ++dt) {
        u16 t4[4];
#pragma unroll
        for (int r = 0; r < 4; ++r) t4[r] = f2bf(O[dt][r] * inv);
        *(uint2*)&orow[dt * 16 + quad * 4] = *(const uint2*)t4;
    }
}

// ---------------------------------------------------------------- launch
extern "C" void kernel_launch(void* const* d_in, const int* in_sizes, int n_in,
                              void* d_out, int out_size, void* d_ws, size_t ws_size,
                              hipStream_t stream) {
    const void* x     = d_in[0];
    const void* key   = d_in[1];
    const void* value = d_in[2];
    const int*  mask  = (const int*)d_in[3];
    const void* Wq    = d_in[4];
    const void* Wk    = d_in[5];
    const void* Wv    = d_in[6];
    const void* Wo    = d_in[7];
    const void* gamma = d_in[8];
    const void* beta  = d_in[9];

    // ws layout (65 MB), time-multiplexed:
    //  @1  xn [8MB] -> mask_u8 after Q-GEMM
    //  @9  kb [16MB] -> q [8MB] @9 + ao [8MB] @17
    //  @25 vb [16MB] -> k [16MB]
    //  @41 vT [16MB]
    //  @57..65 Wqt/Wkt/Wvt/Wot [2MB each]
    char* ws = (char*)d_ws;
    int* flag = (int*)(ws);
    u16* xn  = (u16*)(ws + ( 1ull << 20));
    u8*  mu8 = (u8*) (ws + ( 1ull << 20));
    u16* q   = (u16*)(ws + ( 9ull << 20));
    u16* kb  = (u16*)(ws + ( 9ull << 20));
    u16* ao  = (u16*)(ws + (17ull << 20));
    u16* k   = (u16*)(ws + (25ull << 20));
    u16* vb  = (u16*)(ws + (25ull << 20));
    u16* vT  = (u16*)(ws + (41ull << 20));
    u16* Wqt = (u16*)(ws + (57ull << 20));
    u16* Wkt = (u16*)(ws + (59ull << 20));
    u16* Wvt = (u16*)(ws + (61ull << 20));
    u16* Wot = (u16*)(ws + (63ull << 20));

    const float QSCALE = 0.125f * 1.44269504f;   // d^-0.5 * log2(e) for exp2 softmax

    detect_dtype<<<1, 256, 0, stream>>>((const u32*)x, flag);

    ln_kernel<<<4096, 256, 0, stream>>>(x, gamma, beta, xn, flag);

    dim3 tg(16, 16);
    transpose64<<<tg, 256, 0, stream>>>(Wq, Wqt, 1024, 1024, flag);
    transpose64<<<tg, 256, 0, stream>>>(Wk, Wkt, 1024, 1024, flag);
    transpose64<<<tg, 256, 0, stream>>>(Wv, Wvt, 1024, 1024, flag);
    transpose64<<<tg, 256, 0, stream>>>(Wo, Wot, 1024, 1024, flag);

    conv_bf16<<<4096, 256, 0, stream>>>(key,   kb, flag);
    conv_bf16<<<4096, 256, 0, stream>>>(value, vb, flag);

    // 1-D XCD-grouped grids: M=8192 -> 512 blocks, mdiv=8; M=4096 -> 256, mdiv=4
    gemm128<<<512, 256, 0, stream>>>(vb, Wvt, vT, 8192, 1024, 1024, flag, 0, 1.0f, 1, 8);
    gemm128<<<512, 256, 0, stream>>>(kb, Wkt, k,  8192, 1024, 1024, flag, 0, 1.0f, 0, 8);
    gemm128<<<256, 256, 0, stream>>>(xn, Wqt, q,  4096, 1024, 1024, flag, 0, QSCALE, 0, 4);

    mask_pack<<<2048, 256, 0, stream>>>(mask, mu8);

    attn_kernel<<<1024, 256, 0, stream>>>(q, k, vT, mu8, ao);

    gemm128<<<256, 256, 0, stream>>>(ao, Wot, d_out, 4096, 1024, 1024, flag, 1, 1.0f, 0, 4);
}